// Round 8
// baseline (13.282 us; speedup 1.0000x reference)
//
#include <hip/hip_runtime.h>

// Live computation of the reference (everything else is dead code):
//   inpt[384] = concat(x[64], prev_output[64], state[256])
//   h1[1024]  = relu(w1_0 @ inpt + b1_0)   w1_0: (1024,384) row-major
//   h2[1024]  = relu(w1_1 @ h1   + b1_1)   w1_1: (1024,1024)
//   out[64]   = relu(w1_2 @ h2   + b1_2)   w1_2: (64,1024)
//
// Final structure, per the session's sync ledger:
//   3-dispatch plain      13.26 us  <- this kernel (best, correct)
//   2-dispatch ACQ_REL    19.1  us
//   1-dispatch lean bar   28.5  us
//   1-dispatch spin bar   39.0  us
//   2-dispatch lean fan-in FAILED (stale cross-XCD h2: release wbl2 not
//     provably complete before finalizer's acquire+inv -> G16 violation)
// Kernel-boundary sync (~3-4 us/node) is the only correct AND cheapest
// ordering primitive on gfx950 for this dependency chain. Bodies ~2-4 us
// (weights L2-resident). Remaining time is graph-node overhead: the
// structural floor for a 3-layer dependent chain.

__device__ __forceinline__ float wave_reduce_sum(float v) {
    v += __shfl_xor(v, 32, 64);
    v += __shfl_xor(v, 16, 64);
    v += __shfl_xor(v, 8, 64);
    v += __shfl_xor(v, 4, 64);
    v += __shfl_xor(v, 2, 64);
    v += __shfl_xor(v, 1, 64);
    return v;
}

// Layer 1: K = 384, one row per wave, no LDS, no barriers. The 384-float
// input is identical for all blocks (L1/L2-resident after first touch);
// segment boundaries (64,128) are float4/float2-aligned.
__global__ void __launch_bounds__(256) fc_relu_concat(
        const float* __restrict__ x, const float* __restrict__ po,
        const float* __restrict__ st,
        const float* __restrict__ w, const float* __restrict__ b,
        float* __restrict__ out) {
    const int t = threadIdx.x;
    const int lane = t & 63;
    const int wave = t >> 6;
    const int r = blockIdx.x * 4 + wave;   // [0,1024)

    const float* wr = w + (size_t)r * 384;
    float acc;
    {
        const int i = lane * 4;            // [0,256): x / po / st[0..127]
        const float* src = (i < 64) ? (x + i)
                          : (i < 128) ? (po + (i - 64))
                          : (st + (i - 128));
        float4 wv = *reinterpret_cast<const float4*>(wr + i);
        float4 iv = *reinterpret_cast<const float4*>(src);
        acc = wv.x * iv.x + wv.y * iv.y + wv.z * iv.z + wv.w * iv.w;
    }
    {
        const int j = 256 + lane * 2;      // [256,384): st[128..255]
        float2 wv = *reinterpret_cast<const float2*>(wr + j);
        float2 iv = *reinterpret_cast<const float2*>(st + (j - 128));
        acc += wv.x * iv.x + wv.y * iv.y;
    }
    acc = wave_reduce_sum(acc);
    if (lane == 0) out[r] = fmaxf(acc + b[r], 0.f);
}

// Layers 2/3: K = 1024, ONE ROW PER BLOCK (thread t handles in[4t..4t+3]).
// grid = #rows. Layer 2: 1024 blocks -> 4 blocks/CU -> 16 waves/CU.
__global__ void __launch_bounds__(256) fc_relu_row(
        const float* __restrict__ w, const float* __restrict__ b,
        const float* __restrict__ in, float* __restrict__ out) {
    const int row = blockIdx.x;
    const int t = threadIdx.x;

    float4 wv = *reinterpret_cast<const float4*>(w + (size_t)row * 1024 + t * 4);
    float4 iv = *reinterpret_cast<const float4*>(in + t * 4);
    float acc = wv.x * iv.x + wv.y * iv.y + wv.z * iv.z + wv.w * iv.w;
    acc = wave_reduce_sum(acc);

    __shared__ float s[4];
    if ((t & 63) == 0) s[t >> 6] = acc;
    __syncthreads();
    if (t == 0) {
        float tot = s[0] + s[1] + s[2] + s[3];
        out[row] = fmaxf(tot + b[row], 0.f);
    }
}

extern "C" void kernel_launch(void* const* d_in, const int* in_sizes, int n_in,
                              void* d_out, int out_size, void* d_ws, size_t ws_size,
                              hipStream_t stream) {
    // setup_inputs() dict order:
    // 0:x 1:w1_0 2:b1_0 3:w1_1 4:b1_1 5:w1_2 6:b1_2
    // 7..16: w2_*/b2_*  17..26: w3_*/b3_*
    // 27: prev_output 28: state 29: prev_weight_change 30: prev_bias_change
    const float* x    = (const float*)d_in[0];
    const float* w1_0 = (const float*)d_in[1];
    const float* b1_0 = (const float*)d_in[2];
    const float* w1_1 = (const float*)d_in[3];
    const float* b1_1 = (const float*)d_in[4];
    const float* w1_2 = (const float*)d_in[5];
    const float* b1_2 = (const float*)d_in[6];
    const float* po   = (const float*)d_in[27];
    const float* st   = (const float*)d_in[28];

    float* out = (float*)d_out;          // 64 floats
    float* h1 = (float*)d_ws;            // 1024 floats
    float* h2 = h1 + 1024;               // 1024 floats

    fc_relu_concat<<<256, 256, 0, stream>>>(x, po, st, w1_0, b1_0, h1);
    fc_relu_row<<<1024, 256, 0, stream>>>(w1_1, b1_1, h1, h2);
    fc_relu_row<<<64, 256, 0, stream>>>(w1_2, b1_2, h2, out);
}